// Round 1
// baseline (275.543 us; speedup 1.0000x reference)
//
#include <hip/hip_runtime.h>

// Problem constants (fixed shapes)
#define BB 8192      // batch
#define DZ 1024
#define DS 64
#define DH 4096
#define KEXT (DH + DS)   // 4160: K of GEMM2 = [H | s]

typedef float floatx4 __attribute__((ext_vector_type(4)));
typedef __bf16 bf16x8 __attribute__((ext_vector_type(8)));
typedef __bf16 bf16x4 __attribute__((ext_vector_type(4)));
typedef __attribute__((address_space(1))) void* as1_void_ptr;
typedef __attribute__((address_space(3))) void* as3_void_ptr;

// s_waitcnt immediates (gfx9: vmcnt[3:0] bits0-3 + [5:4] bits15:14,
// expcnt bits6:4, lgkmcnt bits11:8). lgkm=15,exp=7 "unconstrained" base = 3952.
#define WAIT_VM0   3952   // vmcnt(0)
#define WAIT_VM4   3956   // vmcnt(4)
#define WAIT_VM6   3958   // vmcnt(6)
#define WAIT_LGKM0 49279  // lgkmcnt(0), vm/exp unconstrained

__device__ __forceinline__ void async_copy16(const void* g, void* l) {
    // global -> LDS direct copy, 16B/lane; per-lane GLOBAL address,
    // wave-uniform LDS base + lane*16 dest.
    __builtin_amdgcn_global_load_lds((as1_void_ptr)g, (as3_void_ptr)l, 16, 0, 0);
}

__device__ __forceinline__ bf16x4 cvt4(float4 v) {
    bf16x4 o = { (__bf16)v.x, (__bf16)v.y, (__bf16)v.z, (__bf16)v.w };
    return o;
}

// LDS bank-conflict swizzle (both GEMMs):
// Panels are [rows x 32] bf16 row-major => 64B row stride. Unswizzled,
// ds_read_b128 lanes 0-15 hit bank-slots {0,4} only (8-way conflict,
// matched the measured 8.5M SQ_LDS_BANK_CONFLICT). Swizzle 16B chunks
// within each row: chunk' = chunk ^ ((row>>1)&3). Then slot =
// (4*row + chunk') % 8 covers all 8 slots exactly twice per 16-lane
// group -> conflict-free. global_load_lds writes linearly, so the
// SOURCE address carries the same XOR (involution, rule #21):
//   staging thread t (row t>>2, phys chunk t&3) loads global chunk
//   (t&3) ^ ((t>>3)&3).
// Read side folds into the frag base: chunk = (lane>>4) ^ ((lane>>1)&3)
// (row offsets wm*64/128, i*16, ks-panels are all ≡0 mod 4 after >>1).

// ---------------- merged prep kernel (all stores 8B) ----------------
// blocks [0,8192): z->zb; [8192,12288): W1->W1b; [12288,13312): B2b=[W2|C];
// [13312,13824): s -> Hb[:, 4096:4160]
__global__ void prep_all(const float* __restrict__ z, const float* __restrict__ W1,
                         const float* __restrict__ W2, const float* __restrict__ C,
                         const float* __restrict__ s,
                         __bf16* __restrict__ zb, __bf16* __restrict__ W1b,
                         __bf16* __restrict__ B2b, __bf16* __restrict__ Hb) {
    const int b = blockIdx.x, t = threadIdx.x;
    if (b < 8192) {
        int i = b * 256 + t;
        *(bf16x4*)(zb + (size_t)i * 4) = cvt4(((const float4*)z)[i]);
    } else if (b < 12288) {
        int i = (b - 8192) * 256 + t;
        *(bf16x4*)(W1b + (size_t)i * 4) = cvt4(((const float4*)W1)[i]);
    } else if (b < 13312) {
        int j = b - 12288;
        const float* wrow = W2 + (size_t)j * DH;
        const float* crow = C + (size_t)j * DS;
        __bf16* orow = B2b + (size_t)j * KEXT;
        for (int c = t; c < 520; c += 256) {   // 520 chunks of 8 elems
            int h = c * 8;
            const float* src = (h < DH) ? (wrow + h) : (crow + (h - DH));
            *(bf16x4*)(orow + h)     = cvt4(*(const float4*)(src));
            *(bf16x4*)(orow + h + 4) = cvt4(*(const float4*)(src + 4));
        }
    } else {
        int i = (b - 13312) * 256 + t;        // 0 .. 131071 chunks of 4
        int r = i >> 4, k = (i & 15) * 4;
        float4 v = *(const float4*)(s + (size_t)r * DS + k);
        *(bf16x4*)(Hb + (size_t)r * KEXT + DH + k) = cvt4(v);
    }
}

// ---------------- GEMM1: Hb[:, :4096] = relu(zb @ W1b^T + h1) ----------------
// A = zb [8192 x 1024] K-major, B = W1b [4096 x 1024] K-major.
// NEW: 256x256 block tile, 8 waves of 128x64 (2M x 4N, m201 geometry) ->
// 42.7 FLOP per LDS byte (vs 32 at 64x64 waves): per kt, LDS read 98KB
// (~768cy) < MFMA 1241cy, so matrix pipe becomes the long pole.
// BK=32, double-buffered 64KB LDS, gemm2-proven vmcnt pipeline.
__global__ __launch_bounds__(512, 2) void gemm1_relu(
    const __bf16* __restrict__ Ag, const __bf16* __restrict__ Bg,
    const float* __restrict__ h1, __bf16* __restrict__ Hb)
{
    constexpr int ldA = DZ, ldB = DZ, KITER = DZ / 32;
    __shared__ __align__(16) __bf16 As[2 * 256 * 32];   // 32 KB dbuf
    __shared__ __align__(16) __bf16 Bs[2 * 256 * 32];   // 32 KB dbuf

    const int tid = threadIdx.x;
    const int wave = tid >> 6, lane = tid & 63;
    const int wm = wave >> 2, wn = wave & 3;            // 2 x 4 waves
    const int row0 = blockIdx.x * 256;
    const int col0 = blockIdx.y * 256;

    const int csrc = ((tid & 3) ^ ((tid >> 3) & 3)) * 8;   // swizzled src chunk
    const __bf16* pA = Ag + (size_t)(row0 + (tid >> 2)) * ldA + csrc;
    const __bf16* pB = Bg + (size_t)(col0 + (tid >> 2)) * ldB + csrc;

    const int cswz = ((lane >> 4) ^ ((lane >> 1) & 3)) * 8; // swizzled read chunk
    const __bf16* Afrag = As + (wm * 128 + (lane & 15)) * 32 + cswz;
    const __bf16* Bfrag = Bs + (wn * 64  + (lane & 15)) * 32 + cswz;

    floatx4 acc[8][4];
#pragma unroll
    for (int i = 0; i < 8; ++i)
#pragma unroll
        for (int j = 0; j < 4; ++j) acc[i][j] = (floatx4)0.0f;

    // issue tile kt into buffer q (4 copies: A rows 0-127/128-255, B same)
    auto issue = [&](int kt, int q) {
        const __bf16* ak = pA + kt * 32;
        const __bf16* bk = pB + kt * 32;
        __bf16* lA = As + q * 8192 + wave * 512;
        __bf16* lB = Bs + q * 8192 + wave * 512;
        async_copy16(ak,                           lA);
        async_copy16(ak + (size_t)128 * ldA,       lA + 4096);
        async_copy16(bk,                           lB);
        async_copy16(bk + (size_t)128 * ldB,       lB + 4096);
    };

    issue(0, 0);   // prologue

    for (int kt = 0; kt < KITER; ++kt) {
        const int p = kt & 1;
        if (kt + 1 < KITER) {
            issue(kt + 1, p ^ 1);
            __builtin_amdgcn_s_waitcnt(WAIT_VM4);   // prior tile's 4 done
        } else {
            __builtin_amdgcn_s_waitcnt(WAIT_VM0);
        }
        __builtin_amdgcn_s_barrier();

        const __bf16* Ab = Afrag + p * 8192;
        const __bf16* Bb = Bfrag + p * 8192;
        bf16x8 af[8], bfr[4];
#pragma unroll
        for (int i = 0; i < 8; ++i) af[i] = *(const bf16x8*)(Ab + i * 16 * 32);
#pragma unroll
        for (int j = 0; j < 4; ++j) bfr[j] = *(const bf16x8*)(Bb + j * 16 * 32);
#pragma unroll
        for (int i = 0; i < 8; ++i)
#pragma unroll
            for (int j = 0; j < 4; ++j)
                acc[i][j] = __builtin_amdgcn_mfma_f32_16x16x32_bf16(af[i], bfr[j], acc[i][j], 0, 0, 0);

        __builtin_amdgcn_s_waitcnt(WAIT_LGKM0);     // reads of buf p done
        __builtin_amdgcn_s_barrier();               // safe to refill buf p
    }

    // epilogue: C/D layout col = lane&15, row = (lane>>4)*4 + reg
    const int r0 = row0 + wm * 128 + (lane >> 4) * 4;
    const int c0 = col0 + wn * 64 + (lane & 15);
#pragma unroll
    for (int i = 0; i < 8; ++i) {
#pragma unroll
        for (int j = 0; j < 4; ++j) {
            int c = c0 + j * 16;
            float bias = h1[c];
#pragma unroll
            for (int rg = 0; rg < 4; ++rg) {
                int r = r0 + i * 16 + rg;
                float v = acc[i][j][rg] + bias;
                v = v > 0.0f ? v : 0.0f;
                Hb[(size_t)r * KEXT + c] = (__bf16)v;
            }
        }
    }
}

// ---------------- GEMM2: out = Hb @ B2b^T + A*zb + h2 ----------------
// A = Hb [8192 x 4160] K-major, B = B2b [1024 x 4160] K-major. BK=64.
// Grid = 32x8 = 256 blocks = exactly 1/CU -> explicit dbuf raw-barrier
// pipeline (96 KB LDS, free at 1 block/CU). This round: + LDS swizzle
// (the 8.5M bank-conflict cycles were ~15% of kernel cycles).
__global__ __launch_bounds__(512, 2) void gemm2_out(
    const __bf16* __restrict__ Ag, const __bf16* __restrict__ Bg,
    const float* __restrict__ Adiag, const float* __restrict__ h2,
    const __bf16* __restrict__ zb, float* __restrict__ out)
{
    constexpr int ldA = KEXT, ldB = KEXT, KITER = KEXT / 64;
    __shared__ __align__(16) __bf16 As[2 * 256 * 64];   // 64 KB dbuf
    __shared__ __align__(16) __bf16 Bs[2 * 128 * 64];   // 32 KB dbuf

    const int tid = threadIdx.x;
    const int wave = tid >> 6, lane = tid & 63;
    const int wm = wave >> 1, wn = wave & 1;
    const int row0 = blockIdx.x * 256;
    const int col0 = blockIdx.y * 128;

    const int csrc = ((tid & 3) ^ ((tid >> 3) & 3)) * 8;   // swizzled src chunk
    const __bf16* pA = Ag + (size_t)(row0 + (tid >> 2)) * ldA + csrc;
    const __bf16* pB = Bg + (size_t)(col0 + ((tid >> 2) & 127)) * ldB + csrc;

    const int cswz = ((lane >> 4) ^ ((lane >> 1) & 3)) * 8; // swizzled read chunk
    const __bf16* Afrag = As + (wm * 64 + (lane & 15)) * 32 + cswz;
    const __bf16* Bfrag = Bs + (wn * 64 + (lane & 15)) * 32 + cswz;

    floatx4 acc[4][4];
#pragma unroll
    for (int i = 0; i < 4; ++i)
#pragma unroll
        for (int j = 0; j < 4; ++j) acc[i][j] = (floatx4)0.0f;

    // issue tile kt into buffer q (6 copies)
    auto issue = [&](int kt, int q) {
        const __bf16* ak = pA + kt * 64;
        const __bf16* bk = pB + kt * 64;
        __bf16* lA = As + q * 16384 + wave * 512;
        __bf16* lB = Bs + q * 8192  + wave * 512;
        async_copy16(ak,                           lA);
        async_copy16(ak + (size_t)128 * ldA,       lA + 4096);
        async_copy16(ak + 32,                      lA + 8192);
        async_copy16(ak + (size_t)128 * ldA + 32,  lA + 8192 + 4096);
        async_copy16(bk,                           lB);
        async_copy16(bk + 32,                      lB + 4096);
    };

    issue(0, 0);   // prologue

    for (int kt = 0; kt < KITER; ++kt) {
        const int p = kt & 1;
        if (kt + 1 < KITER) {
            issue(kt + 1, p ^ 1);
            __builtin_amdgcn_s_waitcnt(WAIT_VM6);   // prior tile's 6 done; 6 in flight
        } else {
            __builtin_amdgcn_s_waitcnt(WAIT_VM0);
        }
        __builtin_amdgcn_s_barrier();

#pragma unroll
        for (int ks = 0; ks < 2; ++ks) {
            const __bf16* Ab = Afrag + p * 16384 + ks * 8192;
            const __bf16* Bb = Bfrag + p * 8192  + ks * 4096;
            bf16x8 af[4], bfr[4];
#pragma unroll
            for (int i = 0; i < 4; ++i) af[i] = *(const bf16x8*)(Ab + i * 16 * 32);
#pragma unroll
            for (int j = 0; j < 4; ++j) bfr[j] = *(const bf16x8*)(Bb + j * 16 * 32);
#pragma unroll
            for (int i = 0; i < 4; ++i)
#pragma unroll
                for (int j = 0; j < 4; ++j)
                    acc[i][j] = __builtin_amdgcn_mfma_f32_16x16x32_bf16(af[i], bfr[j], acc[i][j], 0, 0, 0);
        }

        __builtin_amdgcn_s_waitcnt(WAIT_LGKM0);     // reads of buf p done
        __builtin_amdgcn_s_barrier();               // safe to refill buf p
    }

    const int r0 = row0 + wm * 64 + (lane >> 4) * 4;
    const int c0 = col0 + wn * 64 + (lane & 15);
#pragma unroll
    for (int i = 0; i < 4; ++i) {
#pragma unroll
        for (int j = 0; j < 4; ++j) {
            const int c = c0 + j * 16;
            const float aj = Adiag[c];
            const float hj = h2[c];
#pragma unroll
            for (int rg = 0; rg < 4; ++rg) {
                const int r = r0 + i * 16 + rg;
                out[(size_t)r * DZ + c] =
                    acc[i][j][rg] + aj * (float)zb[(size_t)r * DZ + c] + hj;
            }
        }
    }
}

// ---------------- launch ----------------

extern "C" void kernel_launch(void* const* d_in, const int* in_sizes, int n_in,
                              void* d_out, int out_size, void* d_ws, size_t ws_size,
                              hipStream_t stream) {
    const float* z  = (const float*)d_in[0];   // [8192,1024]
    const float* s  = (const float*)d_in[1];   // [8192,64]
    const float* A  = (const float*)d_in[2];   // [1024]
    const float* W1 = (const float*)d_in[3];   // [4096,1024]
    const float* W2 = (const float*)d_in[4];   // [1024,4096]
    const float* h1 = (const float*)d_in[5];   // [4096]
    const float* h2 = (const float*)d_in[6];   // [1024]
    const float* C  = (const float*)d_in[7];   // [1024,64]
    float* out = (float*)d_out;

    // workspace layout (bytes): Hb | zb | W1b | B2b  ~= 102 MB total
    char* ws = (char*)d_ws;
    size_t offHb  = 0;
    size_t offZb  = offHb  + (size_t)BB * KEXT * 2;
    size_t offW1b = offZb  + (size_t)BB * DZ * 2;
    size_t offB2b = offW1b + (size_t)DH * DZ * 2;
    __bf16* Hb  = (__bf16*)(ws + offHb);    // [8192 x 4160]
    __bf16* zb  = (__bf16*)(ws + offZb);    // [8192 x 1024]
    __bf16* W1b = (__bf16*)(ws + offW1b);   // [4096 x 1024]
    __bf16* B2b = (__bf16*)(ws + offB2b);   // [1024 x 4160] = [W2 | C]

    prep_all<<<13824, 256, 0, stream>>>(z, W1, W2, C, s, zb, W1b, B2b, Hb);
    gemm1_relu<<<dim3(BB / 256, DH / 256), 512, 0, stream>>>(zb, W1b, h1, Hb);
    gemm2_out<<<dim3(BB / 256, DZ / 128), 512, 0, stream>>>(Hb, B2b, A, h2, zb, out);
}

// Round 2
// 256.685 us; speedup vs baseline: 1.0735x; 1.0735x over previous
//
#include <hip/hip_runtime.h>

// Problem constants (fixed shapes)
#define BB 8192      // batch
#define DZ 1024
#define DS 64
#define DH 4096
#define KEXT (DH + DS)   // 4160: K of GEMM2 = [H | s]

typedef float floatx4 __attribute__((ext_vector_type(4)));
typedef __bf16 bf16x8 __attribute__((ext_vector_type(8)));
typedef __bf16 bf16x4 __attribute__((ext_vector_type(4)));
typedef __attribute__((address_space(1))) void* as1_void_ptr;
typedef __attribute__((address_space(3))) void* as3_void_ptr;

// s_waitcnt immediates (gfx9: vmcnt[3:0] bits0-3 + [5:4] bits15:14,
// expcnt bits6:4, lgkmcnt bits11:8). lgkm=15,exp=7 "unconstrained" base = 3952.
#define WAIT_VM0   3952   // vmcnt(0)
#define WAIT_VM6   3958   // vmcnt(6)
#define WAIT_LGKM0 49279  // lgkmcnt(0), vm/exp unconstrained

__device__ __forceinline__ void async_copy16(const void* g, void* l) {
    // global -> LDS direct copy, 16B/lane; per-lane GLOBAL address,
    // wave-uniform LDS base + lane*16 dest.
    __builtin_amdgcn_global_load_lds((as1_void_ptr)g, (as3_void_ptr)l, 16, 0, 0);
}

__device__ __forceinline__ bf16x4 cvt4(float4 v) {
    bf16x4 o = { (__bf16)v.x, (__bf16)v.y, (__bf16)v.z, (__bf16)v.w };
    return o;
}

// LDS bank-conflict swizzle (VERIFIED round 1: SQ_LDS_BANK_CONFLICT 8.5M -> 0):
// Panels are [rows x 32] bf16 row-major => 64B row stride. Unswizzled,
// ds_read_b128 lanes 0-15 hit bank-slots {0,4} only (8-way conflict).
// Swizzle 16B chunks within each row: chunk' = chunk ^ ((row>>1)&3).
// global_load_lds writes linearly, so the SOURCE address carries the same
// XOR (involution, rule #21): staging thread t loads global chunk
// (t&3) ^ ((t>>3)&3). Read side folds into the frag base:
// chunk = (lane>>4) ^ ((lane>>1)&3) (all row-base offsets ≡ 0 mod 4 rows).

// ---------------- merged prep kernel (all stores 8B) ----------------
// blocks [0,8192): z->zb; [8192,12288): W1->W1b; [12288,13312): B2b=[W2|C];
// [13312,13824): s -> Hb[:, 4096:4160]
__global__ void prep_all(const float* __restrict__ z, const float* __restrict__ W1,
                         const float* __restrict__ W2, const float* __restrict__ C,
                         const float* __restrict__ s,
                         __bf16* __restrict__ zb, __bf16* __restrict__ W1b,
                         __bf16* __restrict__ B2b, __bf16* __restrict__ Hb) {
    const int b = blockIdx.x, t = threadIdx.x;
    if (b < 8192) {
        int i = b * 256 + t;
        *(bf16x4*)(zb + (size_t)i * 4) = cvt4(((const float4*)z)[i]);
    } else if (b < 12288) {
        int i = (b - 8192) * 256 + t;
        *(bf16x4*)(W1b + (size_t)i * 4) = cvt4(((const float4*)W1)[i]);
    } else if (b < 13312) {
        int j = b - 12288;
        const float* wrow = W2 + (size_t)j * DH;
        const float* crow = C + (size_t)j * DS;
        __bf16* orow = B2b + (size_t)j * KEXT;
        for (int c = t; c < 520; c += 256) {   // 520 chunks of 8 elems
            int h = c * 8;
            const float* src = (h < DH) ? (wrow + h) : (crow + (h - DH));
            *(bf16x4*)(orow + h)     = cvt4(*(const float4*)(src));
            *(bf16x4*)(orow + h + 4) = cvt4(*(const float4*)(src + 4));
        }
    } else {
        int i = (b - 13312) * 256 + t;        // 0 .. 131071 chunks of 4
        int r = i >> 4, k = (i & 15) * 4;
        float4 v = *(const float4*)(s + (size_t)r * DS + k);
        *(bf16x4*)(Hb + (size_t)r * KEXT + DH + k) = cvt4(v);
    }
}

// ---------------- GEMM1: Hb[:, :4096] = relu(zb @ W1b^T + h1) ----------------
// A = zb [8192 x 1024] K-major, B = W1b [4096 x 1024] K-major. BK=64,
// single-buffer (r4-proven sync), 48 KB LDS, 3 blocks/CU (6 waves/SIMD).
// REVERTED to round-0 geometry (256x128, 64x64 waves, acc[4][4]=64 AGPR):
// the 256x256 rewrite cost residency (1 block/CU, 2 waves/SIMD) and
// regressed 85->93us. Round-1 ADDITION kept: the LDS swizzle (conflicts
// 8.5M -> 0 verified).
__global__ __launch_bounds__(512, 4) void gemm1_relu(
    const __bf16* __restrict__ Ag, const __bf16* __restrict__ Bg,
    const float* __restrict__ h1, __bf16* __restrict__ Hb)
{
    constexpr int ldA = DZ, ldB = DZ, KITER = DZ / 64;
    __shared__ __align__(16) __bf16 As[256 * 64];   // 32 KB (2 panels of 256x32)
    __shared__ __align__(16) __bf16 Bs[128 * 64];   // 16 KB (2 panels of 128x32)

    const int tid = threadIdx.x;
    const int wave = tid >> 6, lane = tid & 63;
    const int wm = wave >> 1, wn = wave & 1;
    const int row0 = blockIdx.x * 256;
    const int col0 = blockIdx.y * 128;

    const int csrc = ((tid & 3) ^ ((tid >> 3) & 3)) * 8;   // swizzled src chunk
    const __bf16* pA = Ag + (size_t)(row0 + (tid >> 2)) * ldA + csrc;
    const __bf16* pB = Bg + (size_t)(col0 + ((tid >> 2) & 127)) * ldB + csrc;
    __bf16* lA = As + wave * 512;   // + lane*16B implicit (8 waves cover 128 rows)
    __bf16* lB = Bs + wave * 512;

    const int cswz = ((lane >> 4) ^ ((lane >> 1) & 3)) * 8; // swizzled read chunk
    const __bf16* Afrag = As + (wm * 64 + (lane & 15)) * 32 + cswz;
    const __bf16* Bfrag = Bs + (wn * 64 + (lane & 15)) * 32 + cswz;

    floatx4 acc[4][4];
#pragma unroll
    for (int i = 0; i < 4; ++i)
#pragma unroll
        for (int j = 0; j < 4; ++j) acc[i][j] = (floatx4)0.0f;

    for (int kt = 0; kt < KITER; ++kt) {
        const __bf16* ak = pA + kt * 64;
        const __bf16* bk = pB + kt * 64;
        // A: rows 0-127 / 128-255, panels k+0 / k+32
        async_copy16(ak,                           lA);
        async_copy16(ak + (size_t)128 * ldA,       lA + 4096);
        async_copy16(ak + 32,                      lA + 8192);
        async_copy16(ak + (size_t)128 * ldA + 32,  lA + 8192 + 4096);
        // B: 128 rows, panels k+0 / k+32
        async_copy16(bk,                           lB);
        async_copy16(bk + 32,                      lB + 4096);
        __builtin_amdgcn_s_waitcnt(0);
        __syncthreads();

#pragma unroll
        for (int ks = 0; ks < 2; ++ks) {
            bf16x8 af[4], bfr[4];
#pragma unroll
            for (int i = 0; i < 4; ++i) af[i] = *(const bf16x8*)(Afrag + ks * 8192 + i * 16 * 32);
#pragma unroll
            for (int j = 0; j < 4; ++j) bfr[j] = *(const bf16x8*)(Bfrag + ks * 4096 + j * 16 * 32);
#pragma unroll
            for (int i = 0; i < 4; ++i)
#pragma unroll
                for (int j = 0; j < 4; ++j)
                    acc[i][j] = __builtin_amdgcn_mfma_f32_16x16x32_bf16(af[i], bfr[j], acc[i][j], 0, 0, 0);
        }
        __syncthreads();
    }

    // epilogue: C/D layout col = lane&15, row = (lane>>4)*4 + reg
    const int r0 = row0 + wm * 64 + (lane >> 4) * 4;
    const int c0 = col0 + wn * 64 + (lane & 15);
#pragma unroll
    for (int i = 0; i < 4; ++i) {
#pragma unroll
        for (int j = 0; j < 4; ++j) {
            int c = c0 + j * 16;
            float bias = h1[c];
#pragma unroll
            for (int rg = 0; rg < 4; ++rg) {
                int r = r0 + i * 16 + rg;
                float v = acc[i][j][rg] + bias;
                v = v > 0.0f ? v : 0.0f;
                Hb[(size_t)r * KEXT + c] = (__bf16)v;
            }
        }
    }
}

// ---------------- GEMM2: out = Hb @ B2b^T + A*zb + h2 ----------------
// A = Hb [8192 x 4160] K-major, B = B2b [1024 x 4160] K-major. BK=64.
// Grid = 32x8 = 256 blocks = exactly 1/CU -> explicit dbuf raw-barrier
// pipeline (96 KB LDS, free at 1 block/CU). Swizzled (round 1, verified).
__global__ __launch_bounds__(512, 2) void gemm2_out(
    const __bf16* __restrict__ Ag, const __bf16* __restrict__ Bg,
    const float* __restrict__ Adiag, const float* __restrict__ h2,
    const __bf16* __restrict__ zb, float* __restrict__ out)
{
    constexpr int ldA = KEXT, ldB = KEXT, KITER = KEXT / 64;
    __shared__ __align__(16) __bf16 As[2 * 256 * 64];   // 64 KB dbuf
    __shared__ __align__(16) __bf16 Bs[2 * 128 * 64];   // 32 KB dbuf

    const int tid = threadIdx.x;
    const int wave = tid >> 6, lane = tid & 63;
    const int wm = wave >> 1, wn = wave & 1;
    const int row0 = blockIdx.x * 256;
    const int col0 = blockIdx.y * 128;

    const int csrc = ((tid & 3) ^ ((tid >> 3) & 3)) * 8;   // swizzled src chunk
    const __bf16* pA = Ag + (size_t)(row0 + (tid >> 2)) * ldA + csrc;
    const __bf16* pB = Bg + (size_t)(col0 + ((tid >> 2) & 127)) * ldB + csrc;

    const int cswz = ((lane >> 4) ^ ((lane >> 1) & 3)) * 8; // swizzled read chunk
    const __bf16* Afrag = As + (wm * 64 + (lane & 15)) * 32 + cswz;
    const __bf16* Bfrag = Bs + (wn * 64 + (lane & 15)) * 32 + cswz;

    floatx4 acc[4][4];
#pragma unroll
    for (int i = 0; i < 4; ++i)
#pragma unroll
        for (int j = 0; j < 4; ++j) acc[i][j] = (floatx4)0.0f;

    // issue tile kt into buffer q (6 copies)
    auto issue = [&](int kt, int q) {
        const __bf16* ak = pA + kt * 64;
        const __bf16* bk = pB + kt * 64;
        __bf16* lA = As + q * 16384 + wave * 512;
        __bf16* lB = Bs + q * 8192  + wave * 512;
        async_copy16(ak,                           lA);
        async_copy16(ak + (size_t)128 * ldA,       lA + 4096);
        async_copy16(ak + 32,                      lA + 8192);
        async_copy16(ak + (size_t)128 * ldA + 32,  lA + 8192 + 4096);
        async_copy16(bk,                           lB);
        async_copy16(bk + 32,                      lB + 4096);
    };

    issue(0, 0);   // prologue

    for (int kt = 0; kt < KITER; ++kt) {
        const int p = kt & 1;
        if (kt + 1 < KITER) {
            issue(kt + 1, p ^ 1);
            __builtin_amdgcn_s_waitcnt(WAIT_VM6);   // prior tile's 6 done; 6 in flight
        } else {
            __builtin_amdgcn_s_waitcnt(WAIT_VM0);
        }
        __builtin_amdgcn_s_barrier();

#pragma unroll
        for (int ks = 0; ks < 2; ++ks) {
            const __bf16* Ab = Afrag + p * 16384 + ks * 8192;
            const __bf16* Bb = Bfrag + p * 8192  + ks * 4096;
            bf16x8 af[4], bfr[4];
#pragma unroll
            for (int i = 0; i < 4; ++i) af[i] = *(const bf16x8*)(Ab + i * 16 * 32);
#pragma unroll
            for (int j = 0; j < 4; ++j) bfr[j] = *(const bf16x8*)(Bb + j * 16 * 32);
#pragma unroll
            for (int i = 0; i < 4; ++i)
#pragma unroll
                for (int j = 0; j < 4; ++j)
                    acc[i][j] = __builtin_amdgcn_mfma_f32_16x16x32_bf16(af[i], bfr[j], acc[i][j], 0, 0, 0);
        }

        __builtin_amdgcn_s_waitcnt(WAIT_LGKM0);     // reads of buf p done
        __builtin_amdgcn_s_barrier();               // safe to refill buf p
    }

    const int r0 = row0 + wm * 64 + (lane >> 4) * 4;
    const int c0 = col0 + wn * 64 + (lane & 15);
#pragma unroll
    for (int i = 0; i < 4; ++i) {
#pragma unroll
        for (int j = 0; j < 4; ++j) {
            const int c = c0 + j * 16;
            const float aj = Adiag[c];
            const float hj = h2[c];
#pragma unroll
            for (int rg = 0; rg < 4; ++rg) {
                const int r = r0 + i * 16 + rg;
                out[(size_t)r * DZ + c] =
                    acc[i][j][rg] + aj * (float)zb[(size_t)r * DZ + c] + hj;
            }
        }
    }
}

// ---------------- launch ----------------

extern "C" void kernel_launch(void* const* d_in, const int* in_sizes, int n_in,
                              void* d_out, int out_size, void* d_ws, size_t ws_size,
                              hipStream_t stream) {
    const float* z  = (const float*)d_in[0];   // [8192,1024]
    const float* s  = (const float*)d_in[1];   // [8192,64]
    const float* A  = (const float*)d_in[2];   // [1024]
    const float* W1 = (const float*)d_in[3];   // [4096,1024]
    const float* W2 = (const float*)d_in[4];   // [1024,4096]
    const float* h1 = (const float*)d_in[5];   // [4096]
    const float* h2 = (const float*)d_in[6];   // [1024]
    const float* C  = (const float*)d_in[7];   // [1024,64]
    float* out = (float*)d_out;

    // workspace layout (bytes): Hb | zb | W1b | B2b  ~= 102 MB total
    char* ws = (char*)d_ws;
    size_t offHb  = 0;
    size_t offZb  = offHb  + (size_t)BB * KEXT * 2;
    size_t offW1b = offZb  + (size_t)BB * DZ * 2;
    size_t offB2b = offW1b + (size_t)DH * DZ * 2;
    __bf16* Hb  = (__bf16*)(ws + offHb);    // [8192 x 4160]
    __bf16* zb  = (__bf16*)(ws + offZb);    // [8192 x 1024]
    __bf16* W1b = (__bf16*)(ws + offW1b);   // [4096 x 1024]
    __bf16* B2b = (__bf16*)(ws + offB2b);   // [1024 x 4160] = [W2 | C]

    prep_all<<<13824, 256, 0, stream>>>(z, W1, W2, C, s, zb, W1b, B2b, Hb);
    gemm1_relu<<<dim3(BB / 256, DH / 128), 512, 0, stream>>>(zb, W1b, h1, Hb);
    gemm2_out<<<dim3(BB / 256, DZ / 128), 512, 0, stream>>>(Hb, B2b, A, h2, zb, out);
}